// Round 1
// 1080.896 us; speedup vs baseline: 1.0085x; 1.0085x over previous
//
#include <hip/hip_runtime.h>

// FusedLoRA: x[4,4096,4096] f32; 3x (A[4096,8], B[8,4096]) f32
// out[16384][12288] = concat_l( (x @ A_l) @ B_l ), scale = 1.0
//
// Phase 1: xa[16384][24] = x @ [A0|A1|A2]   read-bound  (268 MB x)  ~70 us
// Phase 2: out = xa @ blockdiag(B0,B1,B2)   write-bound (805 MB)
//
// R3 lesson: ROWS_PER_WAVE=4 (acc=96 VGPR) + prefetch + bounds(256,3) spilled.
// Fix: ROWS_PER_WAVE=2 -> acc=48 VGPR; prefetch fits under the ~170-VGPR cap.
// R4 lesson: __builtin_nontemporal_store needs a native clang vector type.
// R5 theory: timed window = harness 3GiB fill (~527us, fixed) + phase1(~70)
//   + phase2(~480?!). Phase 2 at ~1.7 TB/s for a pure streaming write vs
//   6.1 TB/s fillBuffer on the same chip -> suspect the NT/L2-bypass store
//   path loses write-combining. Swap to cached stores (B/xa are tiny vs 4MiB
//   per-XCD L2; nothing to protect) + LDS-stage the xa tile so the row loop
//   has no global-load latency in it.

#define DIM       4096
#define M_ROWS    16384
#define RANK      8
#define NC        24
#define OUT_COLS  12288

typedef float floatx4 __attribute__((ext_vector_type(4)));

// ---------------- Phase 1 ---------------- (unchanged)
#define KC             512       // At = 24*512*4 = 48 KB LDS -> 3 blocks/CU
#define ROWS_PER_WAVE  2
#define ROWS_PER_BLOCK 8         // 4 waves * 2 rows

__launch_bounds__(256, 3)
__global__ void lora_xa_kernel(const float* __restrict__ x,
                               const float* __restrict__ A0,
                               const float* __restrict__ A1,
                               const float* __restrict__ A2,
                               float* __restrict__ xa) {
  // Transposed A chunk: compute read At[c][4*lane] is 16B-contiguous across
  // lanes -> conflict-free ds_read_b128.
  __shared__ float At[NC][KC];

  const int tid  = threadIdx.x;
  const int lane = tid & 63;
  const int wave = tid >> 6;
  const int row0 = blockIdx.x * ROWS_PER_BLOCK + wave * ROWS_PER_WAVE;

  float acc[ROWS_PER_WAVE][NC];                  // 48 VGPR
#pragma unroll
  for (int r = 0; r < ROWS_PER_WAVE; ++r)
#pragma unroll
    for (int c = 0; c < NC; ++c) acc[r][c] = 0.f;

  for (int kb = 0; kb < DIM; kb += KC) {
    // prefetch this chunk's x before the staging barrier (16 VGPR)
    float4 xv[2][ROWS_PER_WAVE];
#pragma unroll
    for (int step = 0; step < 2; ++step)
#pragma unroll
      for (int r = 0; r < ROWS_PER_WAVE; ++r)
        xv[step][r] = *(const float4*)(x + (size_t)(row0 + r) * DIM + kb +
                                       step * 256 + 4 * lane);

    // stage A chunk transposed into LDS:
    // per lora KC*8 floats = 1024 float4; 3 loras = 3072 float4 / 256 thr = 12
#pragma unroll
    for (int j = 0; j < 12; ++j) {
      const int l   = j >> 2;                    // compile-time after unroll
      const int idx = tid + (j & 3) * 256;       // float4 index within lora chunk
      const int dof = idx >> 1;                  // k offset in chunk
      const int rq  = (idx & 1) * 4;             // rank quad: 0 or 4
      const float* Ap = (l == 0) ? A0 : (l == 1) ? A1 : A2;
      const float4 v = *(const float4*)(Ap + (size_t)(kb + dof) * RANK + rq);
      At[l * RANK + rq + 0][dof] = v.x;
      At[l * RANK + rq + 1][dof] = v.y;
      At[l * RANK + rq + 2][dof] = v.z;
      At[l * RANK + rq + 3][dof] = v.w;
    }
    __syncthreads();

#pragma unroll
    for (int step = 0; step < 2; ++step) {
      const int kl = step * 256 + 4 * lane;
#pragma unroll
      for (int c = 0; c < NC; ++c) {
        const float4 av = *(const float4*)(&At[c][kl]);
#pragma unroll
        for (int r = 0; r < ROWS_PER_WAVE; ++r) {
          acc[r][c] = fmaf(xv[step][r].x, av.x, acc[r][c]);
          acc[r][c] = fmaf(xv[step][r].y, av.y, acc[r][c]);
          acc[r][c] = fmaf(xv[step][r].z, av.z, acc[r][c]);
          acc[r][c] = fmaf(xv[step][r].w, av.w, acc[r][c]);
        }
      }
    }
    __syncthreads();
  }

  // 64-lane butterfly reduction per (row, col)
#pragma unroll
  for (int r = 0; r < ROWS_PER_WAVE; ++r)
#pragma unroll
    for (int c = 0; c < NC; ++c) {
      float v = acc[r][c];
#pragma unroll
      for (int off = 32; off > 0; off >>= 1) v += __shfl_xor(v, off, 64);
      acc[r][c] = v;
    }

  float outv[ROWS_PER_WAVE];
#pragma unroll
  for (int c = 0; c < NC; ++c)
#pragma unroll
    for (int r = 0; r < ROWS_PER_WAVE; ++r)
      if (lane == c) outv[r] = acc[r][c];

  if (lane < NC) {
#pragma unroll
    for (int r = 0; r < ROWS_PER_WAVE; ++r)
      xa[(size_t)(row0 + r) * NC + lane] = outv[r];
  }
}

// ---------------- Phase 2 ---------------- (R5: cached stores + LDS xa tile)
#define ROW_TILE        128
#define COLS_PER_BLOCK  1024     // 256 threads * float4; grid 12 x 128

__launch_bounds__(256, 4)
__global__ void lora_expand_kernel(const float* __restrict__ xa,
                                   const float* __restrict__ B0,
                                   const float* __restrict__ B1,
                                   const float* __restrict__ B2,
                                   float* __restrict__ out) {
  __shared__ float sxa[ROW_TILE][RANK];          // 4 KB: this block's xa slice

  const int ctile = blockIdx.x;                 // 0..11
  const int rtile = blockIdx.y;                 // 0..127
  const int l     = ctile >> 2;
  const int o     = (ctile & 3) * COLS_PER_BLOCK + threadIdx.x * 4;
  const float* B  = (l == 0) ? B0 : (l == 1) ? B1 : B2;
  const int row0  = rtile * ROW_TILE;

  // stage xa[row0..row0+127][l*8..l*8+7] -> LDS. thread t: row t/2, half t&1.
  // ds_write addr = t*16 -> contiguous, conflict-free.
  {
    const int r = threadIdx.x >> 1;
    const int h = (threadIdx.x & 1) * 4;
    const float4 v =
        *(const float4*)(xa + (size_t)(row0 + r) * NC + l * RANK + h);
    *(float4*)(&sxa[r][h]) = v;
  }

  float4 b[RANK];                               // 32 VGPR, L2-resident loads
#pragma unroll
  for (int r = 0; r < RANK; ++r)
    b[r] = *(const float4*)(B + (size_t)r * DIM + o);

  __syncthreads();

  const size_t ocol = (size_t)l * DIM + o;

#pragma unroll 8
  for (int i = 0; i < ROW_TILE; ++i) {
    // uniform-address ds_read_b128 x2 -> broadcast, no global latency in loop
    const float4 s0 = *(const float4*)(&sxa[i][0]);
    const float4 s1 = *(const float4*)(&sxa[i][4]);
    const float s[8] = {s0.x, s0.y, s0.z, s0.w, s1.x, s1.y, s1.z, s1.w};

    floatx4 acc = {0.f, 0.f, 0.f, 0.f};
#pragma unroll
    for (int r = 0; r < RANK; ++r) {
      acc.x = fmaf(s[r], b[r].x, acc.x);
      acc.y = fmaf(s[r], b[r].y, acc.y);
      acc.z = fmaf(s[r], b[r].z, acc.z);
      acc.w = fmaf(s[r], b[r].w, acc.w);
    }
    // R5: plain cached store (write-combines through L2 like fillBuffer's
    // 6.1 TB/s path). NT/L2-bypass was the suspected 1.7 TB/s culprit.
    *(floatx4*)(out + (size_t)(row0 + i) * OUT_COLS + ocol) = acc;
  }
}

extern "C" void kernel_launch(void* const* d_in, const int* in_sizes, int n_in,
                              void* d_out, int out_size, void* d_ws, size_t ws_size,
                              hipStream_t stream) {
  const float* x  = (const float*)d_in[0];
  const float* A0 = (const float*)d_in[1];
  const float* B0 = (const float*)d_in[2];
  const float* A1 = (const float*)d_in[3];
  const float* B1 = (const float*)d_in[4];
  const float* A2 = (const float*)d_in[5];
  const float* B2 = (const float*)d_in[6];
  float* out = (float*)d_out;
  float* xa  = (float*)d_ws;                    // 16384*24*4 = 1.5 MB

  if (ws_size < (size_t)M_ROWS * NC * sizeof(float)) return;

  lora_xa_kernel<<<dim3(M_ROWS / ROWS_PER_BLOCK), dim3(256), 0, stream>>>(
      x, A0, A1, A2, xa);
  lora_expand_kernel<<<dim3(12, M_ROWS / ROW_TILE), dim3(256), 0, stream>>>(
      xa, B0, B1, B2, out);
}